// Round 1
// baseline (179.009 us; speedup 1.0000x reference)
//
#include <hip/hip_runtime.h>

#define NN 64
#define NITER_LDS 11   // + 1 folded uniform-v matvec = 12 total. |lambda2|~0.15
                       // => 0.15^12 ~ 1e-10 << fp32 eps. (20 was overkill; if
                       // absmax regresses, bump back to 15.)

// One block (64 threads = 1 wave) per (s,t) matrix. Thread m owns row m of
// M = r_const[s,t,:,:] in registers (64 floats). Power-iterate v <- M v from
// LDS double buffer; column-stochastic => sum(v) invariant, no renorm.
//
// v1 = M * (ones/64) = rowsum/64 is computed directly as the row quarters
// drain from HBM (overlaps load latency, removes one LDS iteration).
//
// blockDim == 64 == one wave: same-wave DS ops are processed in order by the
// LDS pipe, so no s_barrier is needed between the ds_write of v and the
// ds_reads of the next iteration (wave-synchronous LDS idiom). The compiler
// keeps aliasing LDS ops ordered; sched_barrier(0) pins it at zero cost.
__global__ __launch_bounds__(64, 4) void perron_kernel(
    const float* __restrict__ x,
    const float* __restrict__ wt,
    const float* __restrict__ rconst,
    float* __restrict__ ws)
{
    const int st = blockIdx.x;        // 0..4095  (st = s*64 + t)
    const int m  = threadIdx.x;       // 0..63, my row
    const int s  = st >> 6;

    const float* M = rconst + (size_t)st * (NN * NN);   // row-major [m][n]

    // Load my row into registers: 16 x float4 (lane m reads 64B-line m; each
    // line fetched once, later quarters L1-hit). Fold matvec #1 (uniform v0)
    // into the drain: acc = rowsum / 64.
    float4 row[16];
    const float4* M4 = (const float4*)(M + m * NN);
    float acc = 0.0f;
    #pragma unroll
    for (int q = 0; q < 16; ++q) {
        row[q] = M4[q];
        acc += (row[q].x + row[q].y) + (row[q].z + row[q].w);
    }
    acc *= (1.0f / NN);               // v1[m]

    __shared__ float vbuf[2][NN];
    int cur = 0;
    vbuf[cur][m] = acc;

    for (int it = 0; it < NITER_LDS; ++it) {
        __builtin_amdgcn_sched_barrier(0);   // keep ds_write(prev) before reads
        const float4* v4 = (const float4*)vbuf[cur];
        acc = 0.0f;
        #pragma unroll
        for (int q = 0; q < 16; ++q) {
            float4 v = v4[q];               // broadcast ds_read_b128
            acc += row[q].x * v.x;
            acc += row[q].y * v.y;
            acc += row[q].z * v.z;
            acc += row[q].w * v.w;
        }
        cur ^= 1;
        vbuf[cur][m] = acc;                 // sum(v) stays 1 automatically
    }
    __builtin_amdgcn_sched_barrier(0);

    // coef = x[s,t] * wt[s,t] * M[s][s] / v[s]   (uniform scalar loads)
    const float Mss  = M[s * NN + s];
    const float coef = x[st] * wt[st] * Mss / vbuf[cur][s];
    ws[(size_t)st * NN + m] = coef * vbuf[cur][m];   // coalesced 256B store
}

// out[n] = sum_st ws[st*64 + n]; 1 MB total, L2-resident from kernel 1.
__global__ __launch_bounds__(256) void reduce_kernel(
    const float* __restrict__ ws, float* __restrict__ out)
{
    const int n   = blockIdx.x;    // 0..63
    const int tid = threadIdx.x;   // 0..255
    float acc = 0.0f;
    #pragma unroll
    for (int r = 0; r < 16; ++r)
        acc += ws[(size_t)(tid + 256 * r) * NN + n];

    // wave reduce (64 lanes)
    #pragma unroll
    for (int off = 32; off > 0; off >>= 1)
        acc += __shfl_down(acc, off, 64);

    __shared__ float wsum[4];
    if ((tid & 63) == 0) wsum[tid >> 6] = acc;
    __syncthreads();
    if (tid == 0) out[n] = wsum[0] + wsum[1] + wsum[2] + wsum[3];
}

extern "C" void kernel_launch(void* const* d_in, const int* in_sizes, int n_in,
                              void* d_out, int out_size, void* d_ws, size_t ws_size,
                              hipStream_t stream) {
    const float* x      = (const float*)d_in[0];   // (64,64)
    const float* wt     = (const float*)d_in[1];   // (64,64)
    // d_in[2] = weights_r, d_in[3] = r_zeros: unused (weights_r * 0 == 0)
    const float* rconst = (const float*)d_in[4];   // (64,64,64,64)
    float* out = (float*)d_out;                    // (64,)
    float* ws  = (float*)d_ws;                     // needs 4096*64*4 = 1 MB

    perron_kernel<<<dim3(NN * NN), dim3(NN), 0, stream>>>(x, wt, rconst, ws);
    reduce_kernel<<<dim3(NN), dim3(256), 0, stream>>>(ws, out);
}

// Round 2
// 175.626 us; speedup vs baseline: 1.0193x; 1.0193x over previous
//
#include <hip/hip_runtime.h>

#define NN 64
#define NITER 11   // + 1 folded uniform-v matvec = 12 total matvecs.
                   // |lambda2| ~ 0.15 for these column-stochastic matrices
                   // => 0.15^12 ~ 1e-10 << fp32 eps (absmax 0.0 at 12 iters).

// Broadcast lane `lane`'s value of v to all lanes via v_readlane_b32 (VALU,
// SGPR result). With a compile-time-constant lane index this is a single
// instruction, no LDS pipe, no exec-mask concerns (all 64 lanes active).
__device__ __forceinline__ float bcast_lane(float v, int lane) {
    return __uint_as_float(__builtin_amdgcn_readlane(__float_as_uint(v), lane));
}

// One block (64 threads = 1 wave) per (s,t) matrix. Thread m owns row m of
// M = r_const[s,t,:,:] in registers (64 floats). Power-iterate v <- M v
// entirely in registers: v is distributed one element per lane; each matvec
// is 64 readlane-broadcasts + 64 FMAs on the wave's own SIMD. Zero LDS ->
// no contention on the shared per-CU LDS pipe across the 16 resident waves,
// and no barriers. Column-stochastic => sum(v) invariant, no renorm.
//
// v1 = M * (ones/64) = rowsum/64 is computed as the row quarters drain from
// HBM (overlaps load latency, removes one matvec from the loop).
__global__ __launch_bounds__(64, 4) void perron_kernel(
    const float* __restrict__ x,
    const float* __restrict__ wt,
    const float* __restrict__ rconst,
    float* __restrict__ ws)
{
    const int st = blockIdx.x;        // 0..4095  (st = s*64 + t)
    const int m  = threadIdx.x;       // 0..63, my row
    const int s  = st >> 6;

    const float* M = rconst + (size_t)st * (NN * NN);   // row-major [m][n]

    // Load my row into registers: 16 x float4 (lane m reads 64B-line m; all
    // 16 instructions together cover the contiguous 16 KB matrix; every byte
    // fetched exactly once). Fold matvec #1 (uniform v0): acc = rowsum / 64.
    float4 row4[16];
    const float4* M4 = (const float4*)(M + m * NN);
    float acc = 0.0f;
    #pragma unroll
    for (int q = 0; q < 16; ++q) {
        row4[q] = M4[q];
        acc += (row4[q].x + row4[q].y) + (row4[q].z + row4[q].w);
    }
    acc *= (1.0f / NN);               // v1[m], lane m holds v[m]

    for (int it = 0; it < NITER; ++it) {
        const float v = acc;
        float a0 = 0.f, a1 = 0.f, a2 = 0.f, a3 = 0.f;
        #pragma unroll
        for (int q = 0; q < 16; ++q) {   // constant indices only: stays in VGPRs
            a0 += row4[q].x * bcast_lane(v, 4 * q + 0);
            a1 += row4[q].y * bcast_lane(v, 4 * q + 1);
            a2 += row4[q].z * bcast_lane(v, 4 * q + 2);
            a3 += row4[q].w * bcast_lane(v, 4 * q + 3);
        }
        acc = (a0 + a1) + (a2 + a3);     // sum(v) stays 1 automatically
    }

    // coef = x[s,t] * wt[s,t] * M[s][s] / v[s]
    // v[s] via readlane with uniform (SGPR) index; Mss via uniform L2 load.
    const float vs   = bcast_lane(acc, s);
    const float Mss  = M[s * NN + s];
    const float coef = x[st] * wt[st] * Mss / vs;
    ws[(size_t)st * NN + m] = coef * acc;   // coalesced 256B store
}

// out[n] = sum_st ws[st*64 + n]; 1 MB total, L2-resident from kernel 1.
__global__ __launch_bounds__(256) void reduce_kernel(
    const float* __restrict__ ws, float* __restrict__ out)
{
    const int n   = blockIdx.x;    // 0..63
    const int tid = threadIdx.x;   // 0..255
    float acc = 0.0f;
    #pragma unroll
    for (int r = 0; r < 16; ++r)
        acc += ws[(size_t)(tid + 256 * r) * NN + n];

    // wave reduce (64 lanes)
    #pragma unroll
    for (int off = 32; off > 0; off >>= 1)
        acc += __shfl_down(acc, off, 64);

    __shared__ float wsum[4];
    if ((tid & 63) == 0) wsum[tid >> 6] = acc;
    __syncthreads();
    if (tid == 0) out[n] = wsum[0] + wsum[1] + wsum[2] + wsum[3];
}

extern "C" void kernel_launch(void* const* d_in, const int* in_sizes, int n_in,
                              void* d_out, int out_size, void* d_ws, size_t ws_size,
                              hipStream_t stream) {
    const float* x      = (const float*)d_in[0];   // (64,64)
    const float* wt     = (const float*)d_in[1];   // (64,64)
    // d_in[2] = weights_r, d_in[3] = r_zeros: unused (weights_r * 0 == 0)
    const float* rconst = (const float*)d_in[4];   // (64,64,64,64)
    float* out = (float*)d_out;                    // (64,)
    float* ws  = (float*)d_ws;                     // needs 4096*64*4 = 1 MB

    perron_kernel<<<dim3(NN * NN), dim3(NN), 0, stream>>>(x, wt, rconst, ws);
    reduce_kernel<<<dim3(NN), dim3(256), 0, stream>>>(ws, out);
}